// Round 14
// baseline (32.075 us; speedup 1.0000x reference)
//
#include <hip/hip_runtime.h>
#include <hip/hip_bf16.h>

constexpr int B  = 256, S = 2048, K = 16;
constexpr int E  = 20, KE = 17, NI = 30;
constexpr int C  = 32;          // chunks per row
constexpr int L  = S / C;       // 64 steps per chunk (covers t = 1..2047)

typedef float    f4 __attribute__((ext_vector_type(4)));
typedef short    s4 __attribute__((ext_vector_type(4)));
typedef unsigned u2 __attribute__((ext_vector_type(2)));

// pack two f32 -> two bf16 (TRUNCATED) in one u32: [lo=a, hi=b] — 1 instr.
__device__ inline unsigned pk2_trunc(float a, float b) {
  return __builtin_amdgcn_perm(__float_as_uint(b), __float_as_uint(a),
                               0x07060302u);
}

#if __has_builtin(__builtin_amdgcn_mfma_f32_16x16x16bf16_1k)
__device__ inline f4 mfma16(s4 a, s4 b, f4 c) {
  return __builtin_amdgcn_mfma_f32_16x16x16bf16_1k(a, b, c, 0, 0, 0);
}
#else
__device__ inline f4 mfma16(s4 a, s4 b, f4 c) {
  f4 d;
  asm volatile("s_nop 1\n\t"
               "v_mfma_f32_16x16x16_bf16 %0, %1, %2, %3\n\t"
               "s_nop 7\n\ts_nop 7"
               : "=&v"(d) : "v"(a), "v"(b), "v"(c));
  return d;
}
#endif

// ============ fused kernel: one block (16 waves) = one row b ============
// Wave w: chunk pair (cA=w, cB=31-w). Each 64-step chunk is split into 4
// independent 16-step segments (s0 forward -> Y0 = X0^T; s1..s3 backward
// -> X1,X2,X3), merged with 3 MFMAs: M^T = op(X3, op(X2, op(X1, Y0)))
// where op(U,V) = U^T V (D-layout identity: D-layout regs of U serve as
// B-layout of U and A-layout of U^T — validated by the r10..r12 chain).
// exp(em) is staged per-wave into LDS once (also serves 4-elem/lane bwd
// leaves); LDS stage is re-aliased as Ml after a barrier.
__global__ __launch_bounds__(1024, 4) void k_fused(
    const float* __restrict__ em,
    const float* __restrict__ trans,
    const int* __restrict__ tags,
    const int* __restrict__ mask,
    const float* __restrict__ startT,
    const float* __restrict__ endT,
    const float* __restrict__ intent_logit,
    const int* __restrict__ intent_labels,
    const float* __restrict__ entity_logit,
    const int* __restrict__ entity_labels,
    float* __restrict__ rowCrf,
    float* __restrict__ rowInt,
    float* __restrict__ rowE2,
    float* __restrict__ rowCnt) {
  __shared__ float tl[256];
  __shared__ alignas(16) float stage[16 * 2048];  // 128 KB; [0,32KB) reused as Ml
  __shared__ int   sigl[C];
  __shared__ float numl[16];
  __shared__ int   lenl[16];

  int tid = threadIdx.x;                      // 0..1023
  if (tid < 256) tl[tid] = trans[tid];
  __syncthreads();

  int w = tid >> 6, lane = tid & 63;          // wave 0..15
  int b  = blockIdx.x;
  int cA = w;
  int cB = 31 - w;
  int g4 = lane >> 4, j0 = lane & 15;

  int tloA = 1 + cA * L;
  int tloB = 1 + cB * L;
  int WB = min(L, S - tloB);                  // 64, or 63 for cB==31

  float* stA = stage + w * 2048;              // 64 rows x 16 f32 (exp'd)
  float* stB = stA + 1024;

  // ---- stage exp(em) rows into LDS (per-wave private; lane = row) ----
  {
    int tAs = tloA + lane;                    // <= 961+63 = 1024 < S  (WA==64)
    int tBs = tloB + min(lane, WB - 1);       // clamp only for cB==31
    const float* gAs = em + ((size_t)b * S + tAs) * 16;
    const float* gBs = em + ((size_t)b * S + tBs) * 16;
#pragma unroll
    for (int q = 0; q < 4; ++q) {
      f4 va = *(const f4*)(gAs + 4 * q);
      f4 vb = *(const f4*)(gBs + 4 * q);
      f4 ea, eb;
      ea.x = __expf(va.x); ea.y = __expf(va.y);
      ea.z = __expf(va.z); ea.w = __expf(va.w);
      eb.x = __expf(vb.x); eb.y = __expf(vb.y);
      eb.z = __expf(vb.z); eb.w = __expf(vb.w);
      *(f4*)(stA + lane * 16 + 4 * q) = ea;
      *(f4*)(stB + lane * 16 + 4 * q) = eb;
    }
  }

  const int* mrow = mask + b * S;
  bool mvA = (mrow[tloA + lane] != 0);
  bool mvB = (lane < WB) && (mrow[tloB + lane] != 0);

  // numerator gather: issue loads now, reduce AFTER the main loop
  const int* trow = tags + b * S;
  int ttA = tloA + lane;
  int ttB = tloB + min(lane, WB - 1);
  int tacA = trow[ttA], tapA = trow[ttA - 1];
  int tacB = trow[ttB], tapB = trow[ttB - 1];
  float gAv = em[((size_t)b * S + ttA) * 16 + tacA];
  float gBv = em[((size_t)b * S + ttB) * 16 + tacB];

  int nA = __popcll(__ballot(mvA));           // 63 or 64 (len >= S/2)
  int nB = __popcll(__ballot(mvB));           // 0..64, mask monotone

  // leaf constants: forward etF_r = exp(T[4g+r][j0]); backward etT_r = exp(T[j0][4g+r])
  float etF0 = __expf(tl[(4 * g4 + 0) * 16 + j0]);
  float etF1 = __expf(tl[(4 * g4 + 1) * 16 + j0]);
  float etF2 = __expf(tl[(4 * g4 + 2) * 16 + j0]);
  float etF3 = __expf(tl[(4 * g4 + 3) * 16 + j0]);
  float etT0 = __expf(tl[j0 * 16 + 4 * g4 + 0]);
  float etT1 = __expf(tl[j0 * 16 + 4 * g4 + 1]);
  float etT2 = __expf(tl[j0 * 16 + 4 * g4 + 2]);
  float etT3 = __expf(tl[j0 * 16 + 4 * g4 + 3]);

  f4 ID;
  ID.x = (4 * g4 + 0 == j0) ? 1.f : 0.f;
  ID.y = (4 * g4 + 1 == j0) ? 1.f : 0.f;
  ID.z = (4 * g4 + 2 == j0) ? 1.f : 0.f;
  ID.w = (4 * g4 + 3 == j0) ? 1.f : 0.f;
  f4 Y0A = ID, X1A = ID, X2A = ID, X3A = ID;
  f4 Y0B = ID, X1B = ID, X2B = ID, X3B = ID;
  int sigA = 0, sigB = 0;
  const f4 zero4 = {0.f, 0.f, 0.f, 0.f};

// forward step (Y <- op(leafX_t, Y) = D_t^T * Y), leaf e = exp'd em at j0
#define STEPF(st_, row_, ACC_)                                          \
  { float ee = (st_)[(row_) * 16 + j0];                                 \
    unsigned a01 = pk2_trunc(etF0 * ee, etF1 * ee);                     \
    unsigned a23 = pk2_trunc(etF2 * ee, etF3 * ee);                     \
    unsigned b01 = pk2_trunc(ACC_.x, ACC_.y);                           \
    unsigned b23 = pk2_trunc(ACC_.z, ACC_.w);                           \
    ACC_ = mfma16(__builtin_bit_cast(s4, (u2){a01, a23}),               \
                  __builtin_bit_cast(s4, (u2){b01, b23}), zero4); }
// backward step (X <- op(leafY_t, X) = D_t * X), leaf ev = exp'd em[4g..4g+3]
#define STEPB(st_, row_, ACC_)                                          \
  { f4 ev = *(const f4*)((st_) + (row_) * 16 + 4 * g4);                 \
    unsigned a01 = pk2_trunc(etT0 * ev.x, etT1 * ev.y);                 \
    unsigned a23 = pk2_trunc(etT2 * ev.z, etT3 * ev.w);                 \
    unsigned b01 = pk2_trunc(ACC_.x, ACC_.y);                           \
    unsigned b23 = pk2_trunc(ACC_.z, ACC_.w);                           \
    ACC_ = mfma16(__builtin_bit_cast(s4, (u2){a01, a23}),               \
                  __builtin_bit_cast(s4, (u2){b01, b23}), zero4); }
#define RES(ACC_, SIG_)                                                 \
  { unsigned fb = __builtin_amdgcn_readfirstlane(__float_as_uint(ACC_.x));\
    int e = (int)((fb >> 23) & 0xffu) - 127;                            \
    e = max(min(e, 126), -126);                                         \
    float sc = __uint_as_float((unsigned)(127 - e) << 23);              \
    ACC_.x *= sc; ACC_.y *= sc; ACC_.z *= sc; ACC_.w *= sc;             \
    SIG_ += e; }
// combine op: OUT = U^T * V (all D-layout)
#define OPC(U_, V_, OUT_)                                               \
  { unsigned ua = pk2_trunc(U_.x, U_.y), ub = pk2_trunc(U_.z, U_.w);    \
    unsigned va = pk2_trunc(V_.x, V_.y), vb = pk2_trunc(V_.z, V_.w);    \
    OUT_ = mfma16(__builtin_bit_cast(s4, (u2){ua, ub}),                 \
                  __builtin_bit_cast(s4, (u2){va, vb}), zero4); }

  // ---- 8 independent 16-step chains, round-robin interleaved ----
#pragma unroll
  for (int u = 0; u < 16; ++u) {
    STEPF(stA, u, Y0A)                        // A rows 0..15 < 63 <= nA: full
    if (u < nB) STEPF(stB, u, Y0B)
    STEPB(stA, 31 - u, X1A)                   // A rows 16..31: full
    if (31 - u < nB) STEPB(stB, 31 - u, X1B)
    STEPB(stA, 47 - u, X2A)                   // A rows 32..47: full
    if (47 - u < nB) STEPB(stB, 47 - u, X2B)
    if (63 - u < nA) STEPB(stA, 63 - u, X3A)  // only row 63 can be invalid
    if (63 - u < nB) STEPB(stB, 63 - u, X3B)
    if (u == 7 || u == 15) {
      RES(Y0A, sigA) RES(X1A, sigA) RES(X2A, sigA) RES(X3A, sigA)
      RES(Y0B, sigB) RES(X1B, sigB) RES(X2B, sigB) RES(X3B, sigB)
    }
  }

  // ---- merge segments: M^T = op(X3, op(X2, op(X1, Y0))) ----
  f4 oA, pA, MA, oB, pB, MB;
  OPC(X1A, Y0A, oA) RES(oA, sigA)
  OPC(X2A, oA,  pA) RES(pA, sigA)
  OPC(X3A, pA,  MA) RES(MA, sigA)
  OPC(X1B, Y0B, oB) RES(oB, sigB)
  OPC(X2B, oB,  pB) RES(pB, sigB)
  OPC(X3B, pB,  MB) RES(MB, sigB)
#undef STEPF
#undef STEPB
#undef RES
#undef OPC

  // deferred numerator combine + wave reduce
  float numc = 0.f;
  if (lane < nA) numc += tl[tapA * 16 + tacA] + gAv;
  if (lane < nB) numc += tl[tapB * 16 + tacB] + gBv;
#pragma unroll
  for (int o = 1; o < 64; o <<= 1) numc += __shfl_xor(numc, o);

  __syncthreads();                            // stage dead everywhere; alias as Ml

  float* Ml = stage;                          // 32 KB region, flat layout as r10
  int base = (j0 >> 2) * 64 + 16 * g4 + (j0 & 3);
  float* moA = &Ml[cA * 256];
  moA[base + 0]  = MA.x;
  moA[base + 4]  = MA.y;
  moA[base + 8]  = MA.z;
  moA[base + 12] = MA.w;
  float* moB = &Ml[cB * 256];
  moB[base + 0]  = MB.x;
  moB[base + 4]  = MB.y;
  moB[base + 8]  = MB.z;
  moB[base + 12] = MB.w;
  if (lane == 0) {
    sigl[cA] = sigA;
    sigl[cB] = sigB;
    numl[w]  = numc;
    lenl[w]  = nA + nB + (cA == 0 ? 1 : 0);   // t=0 always valid
  }
  __syncthreads();

  if (w == 0) {
    // ---------------- wave 0: CRF combine (verbatim r10) ----------------
    int l = lane, jb = l & 15, ib = l >> 4;

    float numtot = (l < 16) ? numl[l] : 0.f;
    int   lentot = (l < 16) ? lenl[l] : 0;
#pragma unroll
    for (int o = 1; o < 16; o <<= 1) {
      numtot += __shfl_xor(numtot, o);
      lentot += __shfl_xor(lentot, o);
    }

    const float* erow = em + (size_t)b * S * 16;
    float a0v = startT[jb] + erow[jb];
    float m0 = a0v;
#pragma unroll
    for (int o = 1; o < 16; o <<= 1) m0 = fmaxf(m0, __shfl_xor(m0, o));
    float v = __expf(a0v - m0);
    float total = m0;
    int tg0 = tags[(size_t)b * S];
    float num0 = __shfl(a0v, tg0);

    int sv = (l < C) ? sigl[l] : 0;
    const f4* mptr = (const f4*)stage;
    f4 p0 = mptr[0 * 64 + l], p1 = mptr[1 * 64 + l];
    f4 p2 = mptr[2 * 64 + l], p3 = mptr[3 * 64 + l];

#define PROC(p_, c_)                                                         \
    {                                                                        \
      float v0 = __shfl(v, 4 * ib + 0), v1 = __shfl(v, 4 * ib + 1);          \
      float v2 = __shfl(v, 4 * ib + 2), v3 = __shfl(v, 4 * ib + 3);          \
      float sacc = v0 * p_.x + v1 * p_.y + v2 * p_.z + v3 * p_.w;            \
      sacc += __shfl_xor(sacc, 16); sacc += __shfl_xor(sacc, 32);            \
      float mx = sacc;                                                       \
      for (int o = 1; o < 16; o <<= 1) mx = fmaxf(mx, __shfl_xor(mx, o));    \
      int e = (int)((__float_as_uint(mx) >> 23) & 0xffu) - 127;              \
      e = max(min(e, 126), -126);                                            \
      float sc = __uint_as_float((unsigned)(127 - e) << 23);                 \
      v = sacc * sc;                                                         \
      total += (float)(__shfl(sv, (c_)) + e) * 0.6931471805599453f;          \
    }

    for (int cc = 0; cc < C; cc += 4) {
      PROC(p0, cc + 0) if (cc + 4 < C) p0 = mptr[(cc + 4) * 64 + l];
      PROC(p1, cc + 1) if (cc + 4 < C) p1 = mptr[(cc + 5) * 64 + l];
      PROC(p2, cc + 2) if (cc + 4 < C) p2 = mptr[(cc + 6) * 64 + l];
      PROC(p3, cc + 3) if (cc + 4 < C) p3 = mptr[(cc + 7) * 64 + l];
    }
#undef PROC

    float term = v * __expf(endT[jb]);
#pragma unroll
    for (int o = 1; o < 16; o <<= 1) term += __shfl_xor(term, o);
    if (l == 0) {
      float logZ = __logf(term) + total;
      float numb = numtot + num0 + endT[tags[(size_t)b * S + lentot - 1]];
      rowCrf[b] = logZ - numb;
    }
  } else if (w == 1) {
    // ---------------- wave 1: CE partials (verbatim r10) ----------------
    int l = lane;
    const float* row = intent_logit + b * NI;
    float x = (l < NI) ? row[l] : -1e30f;
    float mi = x;
#pragma unroll
    for (int o = 1; o < 64; o <<= 1) mi = fmaxf(mi, __shfl_xor(mi, o));
    float se = (l < NI) ? __expf(x - mi) : 0.f;
#pragma unroll
    for (int o = 1; o < 64; o <<= 1) se += __shfl_xor(se, o);

    float nll2 = 0.f, cnt2 = 0.f;
    if (l < E) {
      const float* er = entity_logit + (size_t)(b * E + l) * KE;
      float me = -1e30f;
      for (int k = 0; k < KE; ++k) me = fmaxf(me, er[k]);
      float ss = 0.f;
      for (int k = 0; k < KE; ++k) ss += __expf(er[k] - me);
      int lb = entity_labels[b * E + l];
      if (lb != 0) { nll2 = -(er[lb] - me - __logf(ss)); cnt2 = 1.f; }
    }
#pragma unroll
    for (int o = 1; o < 64; o <<= 1) {
      nll2 += __shfl_xor(nll2, o);
      cnt2 += __shfl_xor(cnt2, o);
    }
    if (l == 0) {
      int lab = intent_labels[b];
      rowInt[b] = -(row[lab] - mi - __logf(se));
      rowE2[b]  = nll2;
      rowCnt[b] = cnt2;
    }
  }
}

// ============ final: reduce 256 per-row partials ============
__global__ __launch_bounds__(256) void k_final(const float* __restrict__ rowCrf,
                                               const float* __restrict__ rowInt,
                                               const float* __restrict__ rowE2,
                                               const float* __restrict__ rowCnt,
                                               float* __restrict__ out) {
  int tid = threadIdx.x;
  float s0 = rowCrf[tid], s1 = rowInt[tid], s2 = rowE2[tid], s3 = rowCnt[tid];
  __shared__ float r[4][4];
#pragma unroll
  for (int o = 32; o; o >>= 1) {
    s0 += __shfl_down(s0, o); s1 += __shfl_down(s1, o);
    s2 += __shfl_down(s2, o); s3 += __shfl_down(s3, o);
  }
  if ((tid & 63) == 0) {
    r[tid >> 6][0] = s0; r[tid >> 6][1] = s1;
    r[tid >> 6][2] = s2; r[tid >> 6][3] = s3;
  }
  __syncthreads();
  if (tid == 0) {
    float crf = r[0][0] + r[1][0] + r[2][0] + r[3][0];
    float it  = r[0][1] + r[1][1] + r[2][1] + r[3][1];
    float e2  = r[0][2] + r[1][2] + r[2][2] + r[3][2];
    float cn  = r[0][3] + r[1][3] + r[2][3] + r[3][3];
    float le1 = crf / (float)B;
    float li  = it  / (float)B;
    float le2 = e2 / fmaxf(cn, 1.f);
    out[0] = (le1 + le2 + li) / 3.f;
    out[1] = le1;
    out[2] = le2;
    out[3] = li;
  }
}

extern "C" void kernel_launch(void* const* d_in, const int* in_sizes, int n_in,
                              void* d_out, int out_size, void* d_ws, size_t ws_size,
                              hipStream_t stream) {
  const float* em            = (const float*)d_in[0];
  const int*   mask          = (const int*)  d_in[1];
  const float* entity_logit  = (const float*)d_in[2];
  const float* intent_logit  = (const float*)d_in[3];
  const int*   seq_labels    = (const int*)  d_in[4];
  const int*   entity_labels = (const int*)  d_in[5];
  const int*   intent_labels = (const int*)  d_in[6];
  const float* trans         = (const float*)d_in[7];
  const float* startT        = (const float*)d_in[8];
  const float* endT          = (const float*)d_in[9];
  float* out = (float*)d_out;

  char* ws = (char*)d_ws;
  float* rowCrf = (float*)ws;                 // 256 f32
  float* rowInt = (float*)(ws + 1024);        // 256 f32
  float* rowE2  = (float*)(ws + 2048);        // 256 f32
  float* rowCnt = (float*)(ws + 3072);        // 256 f32

  k_fused<<<B, 1024, 0, stream>>>(em, trans, seq_labels, mask, startT, endT,
                                  intent_logit, intent_labels,
                                  entity_logit, entity_labels,
                                  rowCrf, rowInt, rowE2, rowCnt);
  k_final<<<1, 256, 0, stream>>>(rowCrf, rowInt, rowE2, rowCnt, out);
}